// Round 4
// baseline (276.799 us; speedup 1.0000x reference)
//
#include <hip/hip_runtime.h>

#define S_LEN 2048
#define HDIM  512
#define S_T   128     // seq rows per block
#define PH    16      // rows per phase
#define W32   32      // taps (and window depth) per lane-half
// 1/sqrt(2048)
#define INV_SQRT_S 0.02209708691207961f

// Double-buffered h staging only. 64 KB; one 16-wave block per CU.
struct Smem {
    float lh[2][PH][HDIM];
};

__device__ __forceinline__ void lds_barrier() {
    // LDS-only barrier: drain lgkmcnt but leave global loads/stores in flight.
    asm volatile("s_waitcnt lgkmcnt(0)\n\ts_barrier" ::: "memory");
}

// Split-tap conv: lanes (l, l+32) of a wave are the (k<32, k>=32) halves of
// one channel. Per-thread resident state is wr[32]+xw[32] (vs 64+64 before):
// total unified regs ~105 < 128 -> 4 waves/SIMD instead of 2 (the round-3
// occupancy diagnosis). Window slot invariant: slot (blockrow & 31) holds
// x[s - 32*ph] after the insert at that row; OFF = (16*phase) & 31 in {0,16}.
template <int OFF, int BUF>
__device__ __forceinline__ void conv_phase(const float* __restrict__ xb, int sbase,
                                           int c, int ph,
                                           const float (&wr)[W32], float (&xw)[W32],
                                           float (&xp)[8], Smem* sm)
{
#pragma unroll
    for (int j = 0; j < PH; ++j) {
        const float xcur = xp[j & 7];
        if (ph == 0)   // low half owns the x-stream; 8-row slack covers latency
            xp[j & 7] = xb[((sbase + j + 8) & (S_LEN - 1)) * HDIM + c];

        // hand the retiring x[s-32] from low half to high half (its insert)
        const float retire = xw[(OFF + j) & 31];
        const float recv   = __shfl_xor(retire, 32, 64);
        const float vins   = ph ? recv : xcur;
        xw[(OFF + j) & 31] = vins;

        float y0 = 0.f, y1 = 0.f, y2 = 0.f, y3 = 0.f;
#pragma unroll
        for (int u = 0; u < W32; u += 4) {   // taps 32*ph + u, identical code both halves
            y0 = fmaf(wr[u],     xw[(OFF + j - u)     & 31], y0);
            y1 = fmaf(wr[u + 1], xw[(OFF + j - u - 1) & 31], y1);
            y2 = fmaf(wr[u + 2], xw[(OFF + j - u - 2) & 31], y2);
            y3 = fmaf(wr[u + 3], xw[(OFF + j - u - 3) & 31], y3);
        }
        float y = (y0 + y1) + (y2 + y3);
        y += __shfl_xor(y, 32, 64);          // combine tap halves (both sides get total)

        if (ph == 0)                          // wr pre-scaled by INV_SQRT_S: finish = y + x
            sm->lh[BUF][j][c] = y + xcur;
    }
}

// Wave-mapped LN: wave w owns row w (16 waves, 16 rows). One barrier, then
// each wave loads its row (8 regs/lane, 2-way-free LDS), shuffle-reduces,
// normalizes from the SAME regs and stores coalesced.
template <int BUF>
__device__ __forceinline__ void ln_phase(int sbase, int lane, int wv,
                                         const float* __restrict__ gamma,
                                         const float* __restrict__ beta,
                                         float* __restrict__ ob, Smem* sm)
{
    lds_barrier();   // all lh[BUF] writes visible

    const int row = wv;
    float v[8];
    float s = 0.f, q = 0.f;
#pragma unroll
    for (int m = 0; m < 8; ++m) {
        v[m] = sm->lh[BUF][row][lane + 64 * m];   // 2 lanes/bank: conflict-free
        s += v[m];
        q = fmaf(v[m], v[m], q);
    }
#pragma unroll
    for (int d = 1; d < 64; d <<= 1) {
        s += __shfl_xor(s, d, 64);
        q += __shfl_xor(q, d, 64);
    }
    const float mean = s * (1.0f / 512.0f);
    const float rstd = rsqrtf(fmaf(q, 1.0f / 512.0f, -mean * mean) + 1e-12f);

    // gamma/beta reloaded per phase (L1-resident) to keep them out of the
    // conv live range.
    float* op = ob + (size_t)(sbase + row) * HDIM + lane;
#pragma unroll
    for (int m = 0; m < 8; ++m) {
        const float gm = gamma[lane + 64 * m];
        const float bt = beta [lane + 64 * m];
        op[64 * m] = fmaf(v[m] - mean, rstd * gm, bt);
    }
}

// (1024,1): one 16-wave block per CU = 4 waves/SIMD; compiler must fit
// <=128 unified regs/wave (live set ~105, so no scratch expected).
__global__ __launch_bounds__(1024, 1)
void fconv_ln(const float* __restrict__ x, const float* __restrict__ w,
              const float* __restrict__ gamma, const float* __restrict__ beta,
              float* __restrict__ out)
{
    __shared__ Smem sm;
    const int t    = threadIdx.x;
    const int lane = t & 63;
    const int wv   = t >> 6;                  // 0..15
    const int ph   = lane >> 5;               // tap half: 0 -> k<32, 1 -> k>=32
    const int c    = wv * 32 + (lane & 31);   // channel 0..511
    const int b  = blockIdx.x >> 4;           // 16 tiles of 128 rows per batch
    const int s0 = (blockIdx.x & 15) * S_T;

    const float* xb = x   + (size_t)b * S_LEN * HDIM;
    float*       ob = out + (size_t)b * S_LEN * HDIM;

    // 32 taps for this half, pre-scaled by INV_SQRT_S (folds the finish FMA)
    float wr[W32];
#pragma unroll
    for (int u = 0; u < W32; ++u)
        wr[u] = w[(ph * W32 + u) * HDIM + c] * INV_SQRT_S;

    // window init: slot m holds x[(s0 - 32*ph - 32 + m) & 2047]
    // (circular halo is a real dependency: reference conv is circular)
    float xw[W32];
#pragma unroll
    for (int m = 0; m < W32; ++m)
        xw[m] = xb[((s0 - ph * W32 - W32 + m) & (S_LEN - 1)) * HDIM + c];

    // x-stream prefetch (low half only): rows s0 .. s0+7
    float xp[8];
#pragma unroll
    for (int j = 0; j < 8; ++j)
        xp[j] = (ph == 0) ? xb[(s0 + j) * HDIM + c] : 0.f;

#pragma unroll 1   // keep the steady-state body ~13 KB (I-cache)
    for (int grp = 0; grp < 4; ++grp) {
        const int base = s0 + grp * 32;
        conv_phase< 0, 0>(xb, base,      c, ph, wr, xw, xp, &sm);
        ln_phase<0>(base,      lane, wv, gamma, beta, ob, &sm);
        conv_phase<16, 1>(xb, base + 16, c, ph, wr, xw, xp, &sm);
        ln_phase<1>(base + 16, lane, wv, gamma, beta, ob, &sm);
    }
}

extern "C" void kernel_launch(void* const* d_in, const int* in_sizes, int n_in,
                              void* d_out, int out_size, void* d_ws, size_t ws_size,
                              hipStream_t stream) {
    const float* x  = (const float*)d_in[0];   // [32, 2048, 512] fp32
    const float* w  = (const float*)d_in[1];   // [1, 64, 512]   fp32
    const float* g  = (const float*)d_in[2];   // [512]
    const float* b  = (const float*)d_in[3];   // [512]
    float* o        = (float*)d_out;           // [32, 2048, 512] fp32

    (void)in_sizes; (void)n_in; (void)out_size; (void)d_ws; (void)ws_size;
    fconv_ln<<<dim3(32 * (S_LEN / S_T)), dim3(1024), 0, stream>>>(x, w, g, b, o);
}